// Round 5
// baseline (650.843 us; speedup 1.0000x reference)
//
#include <hip/hip_runtime.h>
#include <hip/hip_bf16.h>
#include <stdint.h>

#define EDGES 200000
#define INF   128
#define HID   32
#define NHEAD 4
#define OUTF  128
#define MAXK  16

// combined-projection feature count: q(128) g(128) kv(256) b(4) pad(12)
#define NPAD  528

// LDS row stride in u16 for per-edge 128-col tiles (q/g/x)
#define XPAD  136

typedef unsigned short u16;
typedef __attribute__((ext_vector_type(8))) short bf16x8;   // 8 bf16 = 4 VGPRs
typedef __attribute__((ext_vector_type(4))) float f32x4;

__device__ __forceinline__ u16 f2bf(float f) {   // RNE f32->bf16
  union { float f; uint32_t u; } v; v.f = f;
  uint32_t u = v.u;
  return (u16)((u + 0x7FFFu + ((u >> 16) & 1u)) >> 16);
}
__device__ __forceinline__ float bflo(uint32_t p) {   // low bf16 of packed pair
  union { uint32_t u; float f; } v; v.u = p << 16;
  return v.f;
}
__device__ __forceinline__ float bfhi(uint32_t p) {   // high bf16 of packed pair
  union { uint32_t u; float f; } v; v.u = p & 0xFFFF0000u;
  return v.f;
}

// packed f32x2 -> bf16x2 (RNE), lets compiler emit v_cvt_pk_bf16_f32
__device__ __forceinline__ uint32_t cvtpk_bf16(float lo, float hi) {
  float2 t; t.x = lo; t.y = hi;
  __hip_bfloat162 h = __float22bfloat162_rn(t);
  uint32_t u;
  __builtin_memcpy(&u, &h, 4);
  return u;
}
__device__ __forceinline__ bf16x8 pack8(float4 f0, float4 f1) {
  union { uint32_t u[4]; bf16x8 v; } r;
  r.u[0] = cvtpk_bf16(f0.x, f0.y);
  r.u[1] = cvtpk_bf16(f0.z, f0.w);
  r.u[2] = cvtpk_bf16(f1.x, f1.y);
  r.u[3] = cvtpk_bf16(f1.z, f1.w);
  return r.v;
}
__device__ __forceinline__ float sigm(float x) {
  return 1.0f / (1.0f + __expf(-x));
}

// DPP-based add. bound_ctrl=1, full masks.
template <int CTRL>
__device__ __forceinline__ float dpp_add(float x) {
  int y = __builtin_amdgcn_update_dpp(0, __builtin_bit_cast(int, x),
                                      CTRL, 0xF, 0xF, true);
  return x + __builtin_bit_cast(float, y);
}
// sum within each 8-lane half-row: xor1, xor2, then half-row mirror
__device__ __forceinline__ float row8_sum(float x) {
  x = dpp_add<0xB1>(x);    // quad_perm [1,0,3,2]  (xor 1)
  x = dpp_add<0x4E>(x);    // quad_perm [2,3,0,1]  (xor 2)
  x = dpp_add<0x141>(x);   // row_half_mirror      (swap quads within 8)
  return x;
}

// one 16(n) x 32(e) output tile: A = W rows (M=n), B = Z/x rows (N=e).
// D per lane: col(e) = lane&15, row(n) = (lane>>4)*4 + r  -> 4 consecutive n.
struct AccPair { f32x4 a, b; };
__device__ __forceinline__ AccPair tile_mm(const u16* __restrict__ W, int row0,
                                           int ml, int blk,
                                           const bf16x8 (&zfr)[2][4], int ldw) {
  bf16x8 wfr[4];
#pragma unroll
  for (int kk = 0; kk < 4; ++kk)
    wfr[kk] = *(const bf16x8*)(W + (size_t)(row0 + ml) * ldw + kk * 32 + blk * 8);
  AccPair r;
  r.a = (f32x4){0.f, 0.f, 0.f, 0.f};
  r.b = (f32x4){0.f, 0.f, 0.f, 0.f};
#pragma unroll
  for (int kk = 0; kk < 4; ++kk) {
    r.a = __builtin_amdgcn_mfma_f32_16x16x32_bf16(wfr[kk], zfr[0][kk], r.a, 0, 0, 0);
    r.b = __builtin_amdgcn_mfma_f32_16x16x32_bf16(wfr[kk], zfr[1][kk], r.b, 0, 0, 0);
  }
  return r;
}

// load + bf16-pack the B-operand fragments (32 edges x K=128) for one wave
__device__ __forceinline__ void load_zfr(const float* __restrict__ Z, long e0,
                                         int ml, int blk, bf16x8 (&zfr)[2][4]) {
#pragma unroll
  for (int s = 0; s < 2; ++s) {
    const float* zp = Z + (e0 + s * 16 + ml) * INF + blk * 8;
#pragma unroll
    for (int kk = 0; kk < 4; ++kk) {
      float4 f0 = *(const float4*)(zp + kk * 32);
      float4 f1 = *(const float4*)(zp + kk * 32 + 4);
      zfr[s][kk] = pack8(f0, f1);
    }
  }
}

// ---- per-wave LDS staging so every HBM store covers full 128B lines ----
__device__ __forceinline__ void ds_stage_pair(u16* sb, int ml, int blk, int t,
                                              uint2 pa, uint2 pb) {
  const int col2 = (t * 16 + blk * 4) * 2;          // byte col within 128B row
  const int swz = (ml & 7) << 4;
  *(uint2*)((char*)sb + ((ml * 128 + col2) ^ swz)) = pa;           // eA row
  *(uint2*)((char*)sb + (((16 + ml) * 128 + col2) ^ swz)) = pb;    // eB row
}
__device__ __forceinline__ void flush_group(const u16* sb, int lane,
                                            u16* __restrict__ dst, long e0,
                                            int rowu16, int colu16) {
  const int rr = lane >> 3;            // 8 rows per store inst
  const int c8 = (lane & 7) * 8;       // u16 col within the 64-col group
#pragma unroll
  for (int i = 0; i < 4; ++i) {
    const int row = i * 8 + rr;
    bf16x8 v = *(const bf16x8*)((const char*)sb +
                                ((row * 128 + c8 * 2) ^ ((row & 7) << 4)));
    *(bf16x8*)(dst + (e0 + row) * rowu16 + colu16 + c8) = v;
  }
}

// ---------------------------------------------------------------------------
// Kernel 1: repack all projection weights into one bf16 matrix Wc[NPAD][128]
// rows: q 0..127, g 128..255, kv 256..511 (h-major, k then v), b 512..515
// ---------------------------------------------------------------------------
__global__ __launch_bounds__(256) void prep_kernel(
    const float* __restrict__ Wq, const float* __restrict__ Wk,
    const float* __restrict__ Wv, const float* __restrict__ Wb,
    const float* __restrict__ Wg, const float* __restrict__ Wout,
    u16* __restrict__ Wc, u16* __restrict__ Woutb)
{
  int t = blockIdx.x * 256 + threadIdx.x;
  if (t < NPAD * INF) {
    int n = t >> 7, k = t & 127;
    float v = 0.0f;
    if (n < 128)       v = Wq[n * 128 + k];
    else if (n < 256)  v = Wg[(n - 128) * 128 + k];
    else if (n < 512) {
      int m = n - 256, h = m >> 6, c = m & 63;
      v = (c < 32) ? Wk[(h * 32 + c) * 128 + k] : Wv[(h * 32 + (c - 32)) * 128 + k];
    } else if (n < 516) v = Wb[(n - 512) * 128 + k];
    Wc[t] = f2bf(v);
  } else if (t < NPAD * INF + OUTF * 128) {
    int u = t - NPAD * INF;
    Woutb[u] = f2bf(Wout[u]);
  }
}

// ---------------------------------------------------------------------------
// Kernel 2: projection GEMM for the GATHERED quantities only:
//   kvb[E x 256] = Z @ Wc[256:512]^T,  bb[E x 4] = Z @ Wc[512:516]^T
// Single 16KB stage buffer (DS ops are in-order per wave, so the ping-pong
// parity buffer was unnecessary) -> 8 blocks/CU, entire 1563-block grid
// co-resident in one dispatch round.
// ---------------------------------------------------------------------------
__global__ __launch_bounds__(256) void proj_kernel(
    const float* __restrict__ Z, const u16* __restrict__ Wc,
    u16* __restrict__ kvb, float* __restrict__ bb)
{
  __shared__ u16 stage[4][2048];   // [wave][32 rows x 64 cols]  (16 KB)

  const int wid = threadIdx.x >> 6, lane = threadIdx.x & 63;
  const int ml = lane & 15, blk = lane >> 4;
  const long e0 = (long)blockIdx.x * 128 + wid * 32;
  if (e0 >= EDGES) return;   // EDGES % 32 == 0: waves are all-valid or all-out

  bf16x8 zfr[2][4];
  load_zfr(Z, e0, ml, blk, zfr);

  // --- kv: Wc rows 256..511 in four 4-tile groups -> kvb cols [0,256) ---
  for (int g = 0; g < 4; ++g) {
    u16* sb = stage[wid];
#pragma unroll
    for (int t = 0; t < 4; ++t) {
      AccPair acc = tile_mm(Wc, 256 + (g * 4 + t) * 16, ml, blk, zfr, INF);
      uint2 pa, pb;
      pa.x = cvtpk_bf16(acc.a[0], acc.a[1]); pa.y = cvtpk_bf16(acc.a[2], acc.a[3]);
      pb.x = cvtpk_bf16(acc.b[0], acc.b[1]); pb.y = cvtpk_bf16(acc.b[2], acc.b[3]);
      ds_stage_pair(sb, ml, blk, t, pa, pb);
    }
    flush_group(sb, lane, kvb, e0, 256, g * 64);
  }

  // --- b tile: Wc rows 512..515 ---
  {
    AccPair acc = tile_mm(Wc, 512, ml, blk, zfr, INF);
    if (blk == 0) {   // rows 512..515 only
      *(float4*)(bb + (e0 + ml) * 4) =
          make_float4(acc.a[0], acc.a[1], acc.a[2], acc.a[3]);
      *(float4*)(bb + (e0 + 16 + ml) * 4) =
          make_float4(acc.b[0], acc.b[1], acc.b[2], acc.b[3]);
    }
  }
}

// ---------------------------------------------------------------------------
// Kernel 3: fused q/g projection + gathered attention + output GEMM.
// Block = 4 waves = 32 edges.
//  Phase A: q = Z@Wq^T, g = sigmoid(Z@Wg^T + bg) via MFMA, parked in LDS.
//  Phase B: gathered attention, TWO edges per wave per iteration:
//           lane = (edge-half: lane>>5, head: (lane>>3)&3, 4 dims: lane&7).
//           8B gather loads, 4-FMA dot + 3-step DPP row8 reduce.
//  Phase C: out = x @ Wout^T + bout (2 of 8 tiles per wave), float4 stores.
// ---------------------------------------------------------------------------
__global__ __launch_bounds__(256) void attn_out_kernel(
    const float* __restrict__ Z, const u16* __restrict__ Wc,
    const float* __restrict__ bg,
    const int* __restrict__ klist, const u16* __restrict__ kvb,
    const float* __restrict__ bb, const u16* __restrict__ Woutb,
    const float* __restrict__ bout, float* __restrict__ out)
{
  __shared__ u16 qs[32 * XPAD];
  __shared__ u16 gs[32 * XPAD];
  __shared__ u16 xs[32 * XPAD];

  const int wid = threadIdx.x >> 6;
  const int lane = threadIdx.x & 63;
  const long e0 = (long)blockIdx.x * 32;
  const int ml = lane & 15, blk = lane >> 4;

  // ---- Phase A: q/g projection for this block's 32 edges ----
  {
    bf16x8 zfr[2][4];
    load_zfr(Z, e0, ml, blk, zfr);

#pragma unroll
    for (int t = 0; t < 2; ++t) {
      const int nt = wid * 2 + t;             // q tile in [0,8)
      AccPair acc = tile_mm(Wc, nt * 16, ml, blk, zfr, INF);
      const int n0 = nt * 16 + blk * 4;
      uint2 pa, pb;
      pa.x = cvtpk_bf16(acc.a[0], acc.a[1]); pa.y = cvtpk_bf16(acc.a[2], acc.a[3]);
      pb.x = cvtpk_bf16(acc.b[0], acc.b[1]); pb.y = cvtpk_bf16(acc.b[2], acc.b[3]);
      *(uint2*)(&qs[ml * XPAD + n0]) = pa;
      *(uint2*)(&qs[(16 + ml) * XPAD + n0]) = pb;
    }
#pragma unroll
    for (int t = 0; t < 2; ++t) {
      const int nt = wid * 2 + t;             // g tile in [0,8)
      AccPair acc = tile_mm(Wc, 128 + nt * 16, ml, blk, zfr, INF);
      const int n0 = nt * 16 + blk * 4;
      float4 b4 = *(const float4*)(bg + n0);
      uint2 pa, pb;
      pa.x = cvtpk_bf16(sigm(acc.a[0] + b4.x), sigm(acc.a[1] + b4.y));
      pa.y = cvtpk_bf16(sigm(acc.a[2] + b4.z), sigm(acc.a[3] + b4.w));
      pb.x = cvtpk_bf16(sigm(acc.b[0] + b4.x), sigm(acc.b[1] + b4.y));
      pb.y = cvtpk_bf16(sigm(acc.b[2] + b4.z), sigm(acc.b[3] + b4.w));
      *(uint2*)(&gs[ml * XPAD + n0]) = pa;
      *(uint2*)(&gs[(16 + ml) * XPAD + n0]) = pb;
    }
  }
  __syncthreads();

  // ---- Phase B: gathered attention, 2 edges per wave per iteration ----
  const int eh = lane >> 5;          // edge-half
  const int h  = (lane >> 3) & 3;    // head
  const int l  = lane & 7;           // 4-dim group within head
  const int kvo = h * 64 + l * 4;    // u16 offset of k dims in kv row
  const int qgo = h * 32 + l * 4;    // u16 col in q/g/x row
  const float scale = 0.17677669529663687f;  // 1/sqrt(32)

#pragma unroll 1
  for (int it = 0; it < 4; ++it) {
    const int le = wid * 8 + it * 2 + eh;
    const int e  = (int)e0 + le;

    const uint2 q4 = *(const uint2*)(&qs[le * XPAD + qgo]);
    const uint2 g4 = *(const uint2*)(&gs[le * XPAD + qgo]);
    const float q0 = bflo(q4.x), q1 = bfhi(q4.x);
    const float q2 = bflo(q4.y), q3 = bfhi(q4.y);

    float sc[MAXK];
    uint2 vvm[MAXK];
    const int* kl = klist + (size_t)e * 32;
#pragma unroll
    for (int nb = 0; nb < MAXK; ++nb) {
      const int ii = kl[nb];
      const int jj = kl[16 + nb];
      const bool valid = (ii >= 0);
      const int is = valid ? ii : 0;
      const int js = valid ? jj : 0;
      const u16* kvrow = kvb + (size_t)is * 256;
      uint2 kk4 = *(const uint2*)(kvrow + kvo);        // 4 k dims
      uint2 vv4 = *(const uint2*)(kvrow + kvo + 32);   // 4 v dims
      float p = q0 * bflo(kk4.x) + q1 * bfhi(kk4.x)
              + q2 * bflo(kk4.y) + q3 * bfhi(kk4.y);
      p = row8_sum(p);                                 // head-wide dot (8 lanes)
      float bj = bb[(size_t)js * 4 + h];
      sc[nb]   = valid ? (scale * p + bj) : 0.0f;
      vvm[nb]  = valid ? vv4 : make_uint2(0u, 0u);
    }

    float m = sc[0];
#pragma unroll
    for (int nb = 1; nb < MAXK; ++nb) m = fmaxf(m, sc[nb]);
    float s = 0.f, a0 = 0.f, a1 = 0.f, a2 = 0.f, a3 = 0.f;
#pragma unroll
    for (int nb = 0; nb < MAXK; ++nb) {
      float al = __expf(sc[nb] - m);
      s += al;
      a0 += al * bflo(vvm[nb].x);
      a1 += al * bfhi(vvm[nb].x);
      a2 += al * bflo(vvm[nb].y);
      a3 += al * bfhi(vvm[nb].y);
    }
    float inv = 1.0f / s;
    uint2 xo;
    xo.x = cvtpk_bf16(bflo(g4.x) * a0 * inv, bfhi(g4.x) * a1 * inv);
    xo.y = cvtpk_bf16(bflo(g4.y) * a2 * inv, bfhi(g4.y) * a3 * inv);
    *(uint2*)(&xs[le * XPAD + qgo]) = xo;
  }

  __syncthreads();

  // ---- Phase C: output GEMM, 32 edges x 128 out, K = 128 ----
  bf16x8 xfr[2][4];
#pragma unroll
  for (int s = 0; s < 2; ++s) {
#pragma unroll
    for (int kk = 0; kk < 4; ++kk)
      xfr[s][kk] = *(const bf16x8*)(&xs[(s * 16 + ml) * XPAD + kk * 32 + blk * 8]);
  }

  const long eA = e0 + ml, eB = e0 + 16 + ml;

#pragma unroll
  for (int t = 0; t < 2; ++t) {
    const int nt = wid * 2 + t;
    AccPair acc = tile_mm(Woutb, nt * 16, ml, blk, xfr, 128);
    const int o0 = nt * 16 + blk * 4;
    float4 b4 = *(const float4*)(bout + o0);
    float4 ra = make_float4(acc.a[0] + b4.x, acc.a[1] + b4.y,
                            acc.a[2] + b4.z, acc.a[3] + b4.w);
    float4 rb = make_float4(acc.b[0] + b4.x, acc.b[1] + b4.y,
                            acc.b[2] + b4.z, acc.b[3] + b4.w);
    *(float4*)(out + eA * 128 + o0) = ra;
    *(float4*)(out + eB * 128 + o0) = rb;
  }
}

// ---------------------------------------------------------------------------
extern "C" void kernel_launch(void* const* d_in, const int* in_sizes, int n_in,
                              void* d_out, int out_size, void* d_ws, size_t ws_size,
                              hipStream_t stream) {
  const float* Z     = (const float*)d_in[0];
  const int*   klist = (const int*)  d_in[1];
  const float* Wq    = (const float*)d_in[2];
  const float* Wk    = (const float*)d_in[3];
  const float* Wv    = (const float*)d_in[4];
  const float* Wb    = (const float*)d_in[5];
  const float* Wg    = (const float*)d_in[6];
  const float* bg    = (const float*)d_in[7];
  const float* Wout  = (const float*)d_in[8];
  const float* bout  = (const float*)d_in[9];
  float* out = (float*)d_out;

  char* ws = (char*)d_ws;
  u16*   Wc    = (u16*)(ws);                        //   528*128*2   = 135168
  u16*   Woutb = (u16*)(ws + 135168);               //   128*128*2   =  32768
  u16*   kvb   = (u16*)(ws + 167936);               // E*256*2 = 102.4 MB
  float* bb    = (float*)(ws + 102567936);          // E*4*4   = 3.2 MB

  prep_kernel<<<(NPAD * INF + OUTF * 128 + 255) / 256, 256, 0, stream>>>(
      Wq, Wk, Wv, Wb, Wg, Wout, Wc, Woutb);
  proj_kernel<<<(EDGES + 127) / 128, 256, 0, stream>>>(
      Z, Wc, kvb, bb);
  attn_out_kernel<<<EDGES / 32, 256, 0, stream>>>(
      Z, Wc, bg, klist, kvb, bb, Woutb, bout, out);
}

// Round 6
// 575.035 us; speedup vs baseline: 1.1318x; 1.1318x over previous
//
#include <hip/hip_runtime.h>
#include <hip/hip_bf16.h>
#include <stdint.h>

#define EDGES 200000
#define INF   128
#define HID   32
#define NHEAD 4
#define OUTF  128
#define MAXK  16

// combined-projection feature count: q(128) g(128) kv(256) b(4) pad(12)
#define NPAD  528

// LDS row stride in u16 for per-edge 128-col tiles (q/g/x)
#define XPAD  136

typedef unsigned short u16;
typedef __attribute__((ext_vector_type(8))) short bf16x8;   // 8 bf16 = 4 VGPRs
typedef __attribute__((ext_vector_type(4))) float f32x4;

__device__ __forceinline__ u16 f2bf(float f) {   // RNE f32->bf16
  union { float f; uint32_t u; } v; v.f = f;
  uint32_t u = v.u;
  return (u16)((u + 0x7FFFu + ((u >> 16) & 1u)) >> 16);
}
__device__ __forceinline__ float bflo(uint32_t p) {   // low bf16 of packed pair
  union { uint32_t u; float f; } v; v.u = p << 16;
  return v.f;
}
__device__ __forceinline__ float bfhi(uint32_t p) {   // high bf16 of packed pair
  union { uint32_t u; float f; } v; v.u = p & 0xFFFF0000u;
  return v.f;
}

// packed f32x2 -> bf16x2 (RNE), lets compiler emit v_cvt_pk_bf16_f32
__device__ __forceinline__ uint32_t cvtpk_bf16(float lo, float hi) {
  float2 t; t.x = lo; t.y = hi;
  __hip_bfloat162 h = __float22bfloat162_rn(t);
  uint32_t u;
  __builtin_memcpy(&u, &h, 4);
  return u;
}
__device__ __forceinline__ bf16x8 pack8(float4 f0, float4 f1) {
  union { uint32_t u[4]; bf16x8 v; } r;
  r.u[0] = cvtpk_bf16(f0.x, f0.y);
  r.u[1] = cvtpk_bf16(f0.z, f0.w);
  r.u[2] = cvtpk_bf16(f1.x, f1.y);
  r.u[3] = cvtpk_bf16(f1.z, f1.w);
  return r.v;
}
__device__ __forceinline__ float sigm(float x) {
  return 1.0f / (1.0f + __expf(-x));
}

// DPP-based add within each 16-lane row (one head). bound_ctrl=1, full masks.
template <int CTRL>
__device__ __forceinline__ float dpp_add(float x) {
  int y = __builtin_amdgcn_update_dpp(0, __builtin_bit_cast(int, x),
                                      CTRL, 0xF, 0xF, true);
  return x + __builtin_bit_cast(float, y);
}
__device__ __forceinline__ float row16_sum(float x) {
  x = dpp_add<0xB1>(x);
  x = dpp_add<0x4E>(x);
  x = dpp_add<0x141>(x);
  x = dpp_add<0x140>(x);
  return x;
}

// one 16(n) x 32(e) output tile: A = W rows (M=n), B = Z/x rows (N=e).
// D per lane: col(e) = lane&15, row(n) = (lane>>4)*4 + r  -> 4 consecutive n.
struct AccPair { f32x4 a, b; };
__device__ __forceinline__ AccPair tile_mm(const u16* __restrict__ W, int row0,
                                           int ml, int blk,
                                           const bf16x8 (&zfr)[2][4], int ldw) {
  bf16x8 wfr[4];
#pragma unroll
  for (int kk = 0; kk < 4; ++kk)
    wfr[kk] = *(const bf16x8*)(W + (size_t)(row0 + ml) * ldw + kk * 32 + blk * 8);
  AccPair r;
  r.a = (f32x4){0.f, 0.f, 0.f, 0.f};
  r.b = (f32x4){0.f, 0.f, 0.f, 0.f};
#pragma unroll
  for (int kk = 0; kk < 4; ++kk) {
    r.a = __builtin_amdgcn_mfma_f32_16x16x32_bf16(wfr[kk], zfr[0][kk], r.a, 0, 0, 0);
    r.b = __builtin_amdgcn_mfma_f32_16x16x32_bf16(wfr[kk], zfr[1][kk], r.b, 0, 0, 0);
  }
  return r;
}

// load + bf16-pack the B-operand fragments (32 edges x K=128) for one wave
__device__ __forceinline__ void load_zfr(const float* __restrict__ Z, long e0,
                                         int ml, int blk, bf16x8 (&zfr)[2][4]) {
#pragma unroll
  for (int s = 0; s < 2; ++s) {
    const float* zp = Z + (e0 + s * 16 + ml) * INF + blk * 8;
#pragma unroll
    for (int kk = 0; kk < 4; ++kk) {
      float4 f0 = *(const float4*)(zp + kk * 32);
      float4 f1 = *(const float4*)(zp + kk * 32 + 4);
      zfr[s][kk] = pack8(f0, f1);
    }
  }
}

// ---- per-wave LDS staging so every HBM store covers full 128B lines ----
__device__ __forceinline__ void ds_stage_pair(u16* sb, int ml, int blk, int t,
                                              uint2 pa, uint2 pb) {
  const int col2 = (t * 16 + blk * 4) * 2;          // byte col within 128B row
  const int swz = (ml & 7) << 4;
  *(uint2*)((char*)sb + ((ml * 128 + col2) ^ swz)) = pa;           // eA row
  *(uint2*)((char*)sb + (((16 + ml) * 128 + col2) ^ swz)) = pb;    // eB row
}
__device__ __forceinline__ void flush_group(const u16* sb, int lane,
                                            u16* __restrict__ dst, long e0,
                                            int rowu16, int colu16) {
  const int rr = lane >> 3;            // 8 rows per store inst
  const int c8 = (lane & 7) * 8;       // u16 col within the 64-col group
#pragma unroll
  for (int i = 0; i < 4; ++i) {
    const int row = i * 8 + rr;
    bf16x8 v = *(const bf16x8*)((const char*)sb +
                                ((row * 128 + c8 * 2) ^ ((row & 7) << 4)));
    *(bf16x8*)(dst + (e0 + row) * rowu16 + colu16 + c8) = v;
  }
}

// ---------------------------------------------------------------------------
// Kernel 1: repack all projection weights into one bf16 matrix Wc[NPAD][128]
// rows: q 0..127, g 128..255, kv 256..511 (h-major, k then v), b 512..515
// ---------------------------------------------------------------------------
__global__ __launch_bounds__(256) void prep_kernel(
    const float* __restrict__ Wq, const float* __restrict__ Wk,
    const float* __restrict__ Wv, const float* __restrict__ Wb,
    const float* __restrict__ Wg, const float* __restrict__ Wout,
    u16* __restrict__ Wc, u16* __restrict__ Woutb)
{
  int t = blockIdx.x * 256 + threadIdx.x;
  if (t < NPAD * INF) {
    int n = t >> 7, k = t & 127;
    float v = 0.0f;
    if (n < 128)       v = Wq[n * 128 + k];
    else if (n < 256)  v = Wg[(n - 128) * 128 + k];
    else if (n < 512) {
      int m = n - 256, h = m >> 6, c = m & 63;
      v = (c < 32) ? Wk[(h * 32 + c) * 128 + k] : Wv[(h * 32 + (c - 32)) * 128 + k];
    } else if (n < 516) v = Wb[(n - 512) * 128 + k];
    Wc[t] = f2bf(v);
  } else if (t < NPAD * INF + OUTF * 128) {
    int u = t - NPAD * INF;
    Woutb[u] = f2bf(Wout[u]);
  }
}

// ---------------------------------------------------------------------------
// Kernel 2: projection GEMM for the GATHERED quantities only:
//   kvb[E x 256] = Z @ Wc[256:512]^T,  bb[E x 4] = Z @ Wc[512:516]^T
// ---------------------------------------------------------------------------
__global__ __launch_bounds__(256) void proj_kernel(
    const float* __restrict__ Z, const u16* __restrict__ Wc,
    u16* __restrict__ kvb, float* __restrict__ bb)
{
  __shared__ u16 stage[4][2048];   // [wave][32 rows x 64 cols]  (16 KB)

  const int wid = threadIdx.x >> 6, lane = threadIdx.x & 63;
  const int ml = lane & 15, blk = lane >> 4;
  const long e0 = (long)blockIdx.x * 128 + wid * 32;
  if (e0 >= EDGES) return;   // EDGES % 32 == 0: waves are all-valid or all-out

  bf16x8 zfr[2][4];
  load_zfr(Z, e0, ml, blk, zfr);

  // --- kv: Wc rows 256..511 in four 4-tile groups -> kvb cols [0,256) ---
  for (int g = 0; g < 4; ++g) {
    u16* sb = stage[wid];
#pragma unroll
    for (int t = 0; t < 4; ++t) {
      AccPair acc = tile_mm(Wc, 256 + (g * 4 + t) * 16, ml, blk, zfr, INF);
      uint2 pa, pb;
      pa.x = cvtpk_bf16(acc.a[0], acc.a[1]); pa.y = cvtpk_bf16(acc.a[2], acc.a[3]);
      pb.x = cvtpk_bf16(acc.b[0], acc.b[1]); pb.y = cvtpk_bf16(acc.b[2], acc.b[3]);
      ds_stage_pair(sb, ml, blk, t, pa, pb);
    }
    flush_group(sb, lane, kvb, e0, 256, g * 64);
  }

  // --- b tile: Wc rows 512..515 ---
  {
    AccPair acc = tile_mm(Wc, 512, ml, blk, zfr, INF);
    if (blk == 0) {   // rows 512..515 only
      *(float4*)(bb + (e0 + ml) * 4) =
          make_float4(acc.a[0], acc.a[1], acc.a[2], acc.a[3]);
      *(float4*)(bb + (e0 + 16 + ml) * 4) =
          make_float4(acc.b[0], acc.b[1], acc.b[2], acc.b[3]);
    }
  }
}

// ---------------------------------------------------------------------------
// Kernel 3: fused q/g projection + gathered attention + output GEMM.
// Block = 4 waves = 32 edges (R4 Phase-B structure: ONE edge per wave per
// iteration — the 2-edge variant regressed: lost wave-uniform klist/bb
// addressing and latency hiding). Takes a block offset so the grid can be
// split into several dispatches (diagnostic: surfaces proj in top-5).
// ---------------------------------------------------------------------------
__global__ __launch_bounds__(256) void attn_out_kernel(
    const float* __restrict__ Z, const u16* __restrict__ Wc,
    const float* __restrict__ bg,
    const int* __restrict__ klist, const u16* __restrict__ kvb,
    const float* __restrict__ bb, const u16* __restrict__ Woutb,
    const float* __restrict__ bout, float* __restrict__ out, int bofs)
{
  __shared__ u16 qs[32 * XPAD];
  __shared__ u16 gs[32 * XPAD];
  __shared__ u16 xs[32 * XPAD];

  const int wid = threadIdx.x >> 6;
  const int lane = threadIdx.x & 63;
  const long e0 = (long)(bofs + blockIdx.x) * 32;
  const int ml = lane & 15, blk = lane >> 4;

  // ---- Phase A: q/g projection for this block's 32 edges ----
  {
    bf16x8 zfr[2][4];
    load_zfr(Z, e0, ml, blk, zfr);

#pragma unroll
    for (int t = 0; t < 2; ++t) {
      const int nt = wid * 2 + t;             // q tile in [0,8)
      AccPair acc = tile_mm(Wc, nt * 16, ml, blk, zfr, INF);
      const int n0 = nt * 16 + blk * 4;
      uint2 pa, pb;
      pa.x = cvtpk_bf16(acc.a[0], acc.a[1]); pa.y = cvtpk_bf16(acc.a[2], acc.a[3]);
      pb.x = cvtpk_bf16(acc.b[0], acc.b[1]); pb.y = cvtpk_bf16(acc.b[2], acc.b[3]);
      *(uint2*)(&qs[ml * XPAD + n0]) = pa;
      *(uint2*)(&qs[(16 + ml) * XPAD + n0]) = pb;
    }
#pragma unroll
    for (int t = 0; t < 2; ++t) {
      const int nt = wid * 2 + t;             // g tile in [0,8)
      AccPair acc = tile_mm(Wc, 128 + nt * 16, ml, blk, zfr, INF);
      const int n0 = nt * 16 + blk * 4;
      float4 b4 = *(const float4*)(bg + n0);
      uint2 pa, pb;
      pa.x = cvtpk_bf16(sigm(acc.a[0] + b4.x), sigm(acc.a[1] + b4.y));
      pa.y = cvtpk_bf16(sigm(acc.a[2] + b4.z), sigm(acc.a[3] + b4.w));
      pb.x = cvtpk_bf16(sigm(acc.b[0] + b4.x), sigm(acc.b[1] + b4.y));
      pb.y = cvtpk_bf16(sigm(acc.b[2] + b4.z), sigm(acc.b[3] + b4.w));
      *(uint2*)(&gs[ml * XPAD + n0]) = pa;
      *(uint2*)(&gs[(16 + ml) * XPAD + n0]) = pb;
    }
  }
  __syncthreads();

  // ---- Phase B: gathered attention, one edge per wave-iteration ----
  const int h = lane >> 4;
  const int kvo = h * 64 + (lane & 15) * 2;
  const float scale = 0.17677669529663687f;  // 1/sqrt(32)

#pragma unroll 1
  for (int it = 0; it < 8; ++it) {
    const int le = wid * 8 + it;
    int e = (int)e0 + le;
    e = __builtin_amdgcn_readfirstlane(e);   // wave-uniform -> SGPR

    const uint32_t q2 = *(const uint32_t*)(&qs[le * XPAD + 2 * lane]);
    const uint32_t g2 = *(const uint32_t*)(&gs[le * XPAD + 2 * lane]);
    const float q0 = bflo(q2), q1 = bfhi(q2);

    float sc[MAXK];
    uint32_t vvm[MAXK];
    const int* kl = klist + (size_t)e * 32;
#pragma unroll
    for (int nb = 0; nb < MAXK; ++nb) {
      const int ii = kl[nb];
      const int jj = kl[16 + nb];
      const bool valid = (ii >= 0);
      const int is = valid ? ii : 0;
      const int js = valid ? jj : 0;
      const u16* kvrow = kvb + (size_t)is * 256;
      uint32_t kki = *(const uint32_t*)(kvrow + kvo);        // k pair
      uint32_t vvi = *(const uint32_t*)(kvrow + kvo + 32);   // v pair
      float p = q0 * bflo(kki) + q1 * bfhi(kki);
      p = row16_sum(p);                                      // head-wide dot
      float bj = bb[(size_t)js * 4 + h];
      sc[nb]  = valid ? (scale * p + bj) : 0.0f;
      vvm[nb] = valid ? vvi : 0u;
    }

    float m = sc[0];
#pragma unroll
    for (int nb = 1; nb < MAXK; ++nb) m = fmaxf(m, sc[nb]);
    float s = 0.f, a0 = 0.f, a1 = 0.f;
#pragma unroll
    for (int nb = 0; nb < MAXK; ++nb) {
      float al = __expf(sc[nb] - m);
      s += al;
      a0 += al * bflo(vvm[nb]);
      a1 += al * bfhi(vvm[nb]);
    }
    float inv = 1.0f / s;
    uint32_t xo = cvtpk_bf16(bflo(g2) * a0 * inv, bfhi(g2) * a1 * inv);
    *(uint32_t*)(&xs[le * XPAD + 2 * lane]) = xo;   // contiguous 256B: no conflict
  }

  __syncthreads();

  // ---- Phase C: output GEMM, 32 edges x 128 out, K = 128 ----
  bf16x8 xfr[2][4];
#pragma unroll
  for (int s = 0; s < 2; ++s) {
#pragma unroll
    for (int kk = 0; kk < 4; ++kk)
      xfr[s][kk] = *(const bf16x8*)(&xs[(s * 16 + ml) * XPAD + kk * 32 + blk * 8]);
  }

  const long eA = e0 + ml, eB = e0 + 16 + ml;

#pragma unroll
  for (int t = 0; t < 2; ++t) {
    const int nt = wid * 2 + t;
    AccPair acc = tile_mm(Woutb, nt * 16, ml, blk, xfr, 128);
    const int o0 = nt * 16 + blk * 4;
    float4 b4 = *(const float4*)(bout + o0);
    float4 ra = make_float4(acc.a[0] + b4.x, acc.a[1] + b4.y,
                            acc.a[2] + b4.z, acc.a[3] + b4.w);
    float4 rb = make_float4(acc.b[0] + b4.x, acc.b[1] + b4.y,
                            acc.b[2] + b4.z, acc.b[3] + b4.w);
    *(float4*)(out + eA * 128 + o0) = ra;
    *(float4*)(out + eB * 128 + o0) = rb;
  }
}

// ---------------------------------------------------------------------------
extern "C" void kernel_launch(void* const* d_in, const int* in_sizes, int n_in,
                              void* d_out, int out_size, void* d_ws, size_t ws_size,
                              hipStream_t stream) {
  const float* Z     = (const float*)d_in[0];
  const int*   klist = (const int*)  d_in[1];
  const float* Wq    = (const float*)d_in[2];
  const float* Wk    = (const float*)d_in[3];
  const float* Wv    = (const float*)d_in[4];
  const float* Wb    = (const float*)d_in[5];
  const float* Wg    = (const float*)d_in[6];
  const float* bg    = (const float*)d_in[7];
  const float* Wout  = (const float*)d_in[8];
  const float* bout  = (const float*)d_in[9];
  float* out = (float*)d_out;

  char* ws = (char*)d_ws;
  u16*   Wc    = (u16*)(ws);                        //   528*128*2   = 135168
  u16*   Woutb = (u16*)(ws + 135168);               //   128*128*2   =  32768
  u16*   kvb   = (u16*)(ws + 167936);               // E*256*2 = 102.4 MB
  float* bb    = (float*)(ws + 102567936);          // E*4*4   = 3.2 MB

  prep_kernel<<<(NPAD * INF + OUTF * 128 + 255) / 256, 256, 0, stream>>>(
      Wq, Wk, Wv, Wb, Wg, Wout, Wc, Woutb);
  proj_kernel<<<(EDGES + 127) / 128, 256, 0, stream>>>(
      Z, Wc, kvb, bb);
  // attn split into 4 dispatches (diagnostic: lets proj surface in the
  // top-5 counter table; launches are ~free under graph capture).
  const int TOTB = EDGES / 32;                      // 6250
  const int QB = 1563;                              // 1563*3 + 1561 = 6250
  for (int d = 0; d < 4; ++d) {
    const int bofs = d * QB;
    const int nb = (d < 3) ? QB : (TOTB - 3 * QB);
    attn_out_kernel<<<nb, 256, 0, stream>>>(
        Z, Wc, bg, klist, kvb, bb, Woutb, bout, out, bofs);
  }
}

// Round 7
// 504.149 us; speedup vs baseline: 1.2910x; 1.1406x over previous
//
#include <hip/hip_runtime.h>
#include <hip/hip_bf16.h>
#include <stdint.h>

#define EDGES 200000
#define INF   128
#define HID   32
#define NHEAD 4
#define OUTF  128
#define MAXK  16

// combined-projection feature count: q(128) g(128) kv(256) b(4) pad(12)
#define NPAD  528

// LDS row stride in u16 for per-edge 128-col tiles (q/g/x)
#define XPAD  136

typedef unsigned short u16;
typedef __attribute__((ext_vector_type(8))) short bf16x8;   // 8 bf16 = 4 VGPRs
typedef __attribute__((ext_vector_type(4))) float f32x4;

__device__ __forceinline__ u16 f2bf(float f) {   // RNE f32->bf16
  union { float f; uint32_t u; } v; v.f = f;
  uint32_t u = v.u;
  return (u16)((u + 0x7FFFu + ((u >> 16) & 1u)) >> 16);
}
__device__ __forceinline__ float bflo(uint32_t p) {   // low bf16 of packed pair
  union { uint32_t u; float f; } v; v.u = p << 16;
  return v.f;
}
__device__ __forceinline__ float bfhi(uint32_t p) {   // high bf16 of packed pair
  union { uint32_t u; float f; } v; v.u = p & 0xFFFF0000u;
  return v.f;
}

// packed f32x2 -> bf16x2 (RNE), lets compiler emit v_cvt_pk_bf16_f32
__device__ __forceinline__ uint32_t cvtpk_bf16(float lo, float hi) {
  float2 t; t.x = lo; t.y = hi;
  __hip_bfloat162 h = __float22bfloat162_rn(t);
  uint32_t u;
  __builtin_memcpy(&u, &h, 4);
  return u;
}
__device__ __forceinline__ bf16x8 pack8(float4 f0, float4 f1) {
  union { uint32_t u[4]; bf16x8 v; } r;
  r.u[0] = cvtpk_bf16(f0.x, f0.y);
  r.u[1] = cvtpk_bf16(f0.z, f0.w);
  r.u[2] = cvtpk_bf16(f1.x, f1.y);
  r.u[3] = cvtpk_bf16(f1.z, f1.w);
  return r.v;
}
__device__ __forceinline__ float sigm(float x) {
  return 1.0f / (1.0f + __expf(-x));
}

// DPP-based add within each 16-lane row (one head). bound_ctrl=1, full masks.
template <int CTRL>
__device__ __forceinline__ float dpp_add(float x) {
  int y = __builtin_amdgcn_update_dpp(0, __builtin_bit_cast(int, x),
                                      CTRL, 0xF, 0xF, true);
  return x + __builtin_bit_cast(float, y);
}
__device__ __forceinline__ float row16_sum(float x) {
  x = dpp_add<0xB1>(x);
  x = dpp_add<0x4E>(x);
  x = dpp_add<0x141>(x);
  x = dpp_add<0x140>(x);
  return x;
}

// one 16(n) x 32(e) output tile: A = W rows (M=n), B = Z/x rows (N=e).
// D per lane: col(e) = lane&15, row(n) = (lane>>4)*4 + r  -> 4 consecutive n.
struct AccPair { f32x4 a, b; };
__device__ __forceinline__ AccPair tile_mm(const u16* __restrict__ W, int row0,
                                           int ml, int blk,
                                           const bf16x8 (&zfr)[2][4], int ldw) {
  bf16x8 wfr[4];
#pragma unroll
  for (int kk = 0; kk < 4; ++kk)
    wfr[kk] = *(const bf16x8*)(W + (size_t)(row0 + ml) * ldw + kk * 32 + blk * 8);
  AccPair r;
  r.a = (f32x4){0.f, 0.f, 0.f, 0.f};
  r.b = (f32x4){0.f, 0.f, 0.f, 0.f};
#pragma unroll
  for (int kk = 0; kk < 4; ++kk) {
    r.a = __builtin_amdgcn_mfma_f32_16x16x32_bf16(wfr[kk], zfr[0][kk], r.a, 0, 0, 0);
    r.b = __builtin_amdgcn_mfma_f32_16x16x32_bf16(wfr[kk], zfr[1][kk], r.b, 0, 0, 0);
  }
  return r;
}

// load + bf16-pack the B-operand fragments (32 edges x K=128) for one wave
__device__ __forceinline__ void load_zfr(const float* __restrict__ Z, long e0,
                                         int ml, int blk, bf16x8 (&zfr)[2][4]) {
#pragma unroll
  for (int s = 0; s < 2; ++s) {
    const float* zp = Z + (e0 + s * 16 + ml) * INF + blk * 8;
#pragma unroll
    for (int kk = 0; kk < 4; ++kk) {
      float4 f0 = *(const float4*)(zp + kk * 32);
      float4 f1 = *(const float4*)(zp + kk * 32 + 4);
      zfr[s][kk] = pack8(f0, f1);
    }
  }
}

// ---- per-wave LDS staging so every HBM store covers full 128B lines ----
__device__ __forceinline__ void ds_stage_pair(u16* sb, int ml, int blk, int t,
                                              uint2 pa, uint2 pb) {
  const int col2 = (t * 16 + blk * 4) * 2;          // byte col within 128B row
  const int swz = (ml & 7) << 4;
  *(uint2*)((char*)sb + ((ml * 128 + col2) ^ swz)) = pa;           // eA row
  *(uint2*)((char*)sb + (((16 + ml) * 128 + col2) ^ swz)) = pb;    // eB row
}
__device__ __forceinline__ void flush_group(const u16* sb, int lane,
                                            u16* __restrict__ dst, long e0,
                                            int rowu16, int colu16) {
  const int rr = lane >> 3;            // 8 rows per store inst
  const int c8 = (lane & 7) * 8;       // u16 col within the 64-col group
#pragma unroll
  for (int i = 0; i < 4; ++i) {
    const int row = i * 8 + rr;
    bf16x8 v = *(const bf16x8*)((const char*)sb +
                                ((row * 128 + c8 * 2) ^ ((row & 7) << 4)));
    *(bf16x8*)(dst + (e0 + row) * rowu16 + colu16 + c8) = v;
  }
}

// ---------------------------------------------------------------------------
// Kernel 1: repack all projection weights into one bf16 matrix Wc[NPAD][128]
// rows: q 0..127, g 128..255, kv 256..511 (h-major, k then v), b 512..515
// ---------------------------------------------------------------------------
__global__ __launch_bounds__(256) void prep_kernel(
    const float* __restrict__ Wq, const float* __restrict__ Wk,
    const float* __restrict__ Wv, const float* __restrict__ Wb,
    const float* __restrict__ Wg, const float* __restrict__ Wout,
    u16* __restrict__ Wc, u16* __restrict__ Woutb)
{
  int t = blockIdx.x * 256 + threadIdx.x;
  if (t < NPAD * INF) {
    int n = t >> 7, k = t & 127;
    float v = 0.0f;
    if (n < 128)       v = Wq[n * 128 + k];
    else if (n < 256)  v = Wg[(n - 128) * 128 + k];
    else if (n < 512) {
      int m = n - 256, h = m >> 6, c = m & 63;
      v = (c < 32) ? Wk[(h * 32 + c) * 128 + k] : Wv[(h * 32 + (c - 32)) * 128 + k];
    } else if (n < 516) v = Wb[(n - 512) * 128 + k];
    Wc[t] = f2bf(v);
  } else if (t < NPAD * INF + OUTF * 128) {
    int u = t - NPAD * INF;
    Woutb[u] = f2bf(Wout[u]);
  }
}

// ---------------------------------------------------------------------------
// Kernel 2: projection GEMM for the GATHERED quantities only:
//   kvb[E x 256] = Z @ Wc[256:512]^T,  bb[E x 4] = Z @ Wc[512:516]^T
// R6 counters showed proj is LATENCY-bound (VALU 6%, MFMA 5%, HBM 19%,
// occ 40%) with only 1563 blocks. Restructured: 64 edges/block (3125
// blocks), wave-pairs share a 32-edge set; wave A does kv tiles 0..7
// (cols 0..128), wave B does tiles 8..15 (cols 128..256) + b. Per-wave
// serial chain halves, TLP doubles. Z loads duplicate within a pair (L1).
// ---------------------------------------------------------------------------
__global__ __launch_bounds__(256) void proj_kernel(
    const float* __restrict__ Z, const u16* __restrict__ Wc,
    u16* __restrict__ kvb, float* __restrict__ bb)
{
  __shared__ u16 stage[4][2048];   // [wave][32 rows x 64 cols]  (16 KB)

  const int wid = threadIdx.x >> 6, lane = threadIdx.x & 63;
  const int ml = lane & 15, blk = lane >> 4;
  const int pairId = wid >> 1;     // which 32-edge set of the block
  const int half   = wid & 1;      // tile split within the pair
  const long e0 = (long)blockIdx.x * 64 + pairId * 32;

  bf16x8 zfr[2][4];
  load_zfr(Z, e0, ml, blk, zfr);

  // two 4-tile groups per wave -> kvb col range [half*128, half*128+128)
  for (int g = 0; g < 2; ++g) {
    const int gg = half * 2 + g;   // group 0..3
    u16* sb = stage[wid];
#pragma unroll
    for (int t = 0; t < 4; ++t) {
      AccPair acc = tile_mm(Wc, 256 + (gg * 4 + t) * 16, ml, blk, zfr, INF);
      uint2 pa, pb;
      pa.x = cvtpk_bf16(acc.a[0], acc.a[1]); pa.y = cvtpk_bf16(acc.a[2], acc.a[3]);
      pb.x = cvtpk_bf16(acc.b[0], acc.b[1]); pb.y = cvtpk_bf16(acc.b[2], acc.b[3]);
      ds_stage_pair(sb, ml, blk, t, pa, pb);
    }
    flush_group(sb, lane, kvb, e0, 256, gg * 64);
  }

  // --- b tile: Wc rows 512..515 (wave B of each pair) ---
  if (half == 1) {
    AccPair acc = tile_mm(Wc, 512, ml, blk, zfr, INF);
    if (blk == 0) {   // rows 512..515 only
      *(float4*)(bb + (e0 + ml) * 4) =
          make_float4(acc.a[0], acc.a[1], acc.a[2], acc.a[3]);
      *(float4*)(bb + (e0 + 16 + ml) * 4) =
          make_float4(acc.b[0], acc.b[1], acc.b[2], acc.b[3]);
    }
  }
}

// ---------------------------------------------------------------------------
// Kernel 3: fused q/g projection + gathered attention + output GEMM.
// Block = 4 waves = 32 edges, single dispatch (the 4-way split cost ~90us
// in dispatch drains). xs ALIASES qs: phase B reads q[le] then overwrites
// the same LDS row with x[le] within the same wave-iteration (rows are
// wave-exclusive in phase B, DS ops are in-order per wave) -> LDS 26->17.4
// KB -> 9 blocks/CU by LDS, occupancy toward 32 waves/CU.
// ---------------------------------------------------------------------------
__global__ __launch_bounds__(256) void attn_out_kernel(
    const float* __restrict__ Z, const u16* __restrict__ Wc,
    const float* __restrict__ bg,
    const int* __restrict__ klist, const u16* __restrict__ kvb,
    const float* __restrict__ bb, const u16* __restrict__ Woutb,
    const float* __restrict__ bout, float* __restrict__ out)
{
  __shared__ u16 qs[32 * XPAD];    // q in phase A/B, x in phase B/C (aliased)
  __shared__ u16 gs[32 * XPAD];

  const int wid = threadIdx.x >> 6;
  const int lane = threadIdx.x & 63;
  const long e0 = (long)blockIdx.x * 32;
  const int ml = lane & 15, blk = lane >> 4;

  // ---- Phase A: q/g projection for this block's 32 edges ----
  {
    bf16x8 zfr[2][4];
    load_zfr(Z, e0, ml, blk, zfr);

#pragma unroll
    for (int t = 0; t < 2; ++t) {
      const int nt = wid * 2 + t;             // q tile in [0,8)
      AccPair acc = tile_mm(Wc, nt * 16, ml, blk, zfr, INF);
      const int n0 = nt * 16 + blk * 4;
      uint2 pa, pb;
      pa.x = cvtpk_bf16(acc.a[0], acc.a[1]); pa.y = cvtpk_bf16(acc.a[2], acc.a[3]);
      pb.x = cvtpk_bf16(acc.b[0], acc.b[1]); pb.y = cvtpk_bf16(acc.b[2], acc.b[3]);
      *(uint2*)(&qs[ml * XPAD + n0]) = pa;
      *(uint2*)(&qs[(16 + ml) * XPAD + n0]) = pb;
    }
#pragma unroll
    for (int t = 0; t < 2; ++t) {
      const int nt = wid * 2 + t;             // g tile in [0,8)
      AccPair acc = tile_mm(Wc, 128 + nt * 16, ml, blk, zfr, INF);
      const int n0 = nt * 16 + blk * 4;
      float4 b4 = *(const float4*)(bg + n0);
      uint2 pa, pb;
      pa.x = cvtpk_bf16(sigm(acc.a[0] + b4.x), sigm(acc.a[1] + b4.y));
      pa.y = cvtpk_bf16(sigm(acc.a[2] + b4.z), sigm(acc.a[3] + b4.w));
      pb.x = cvtpk_bf16(sigm(acc.b[0] + b4.x), sigm(acc.b[1] + b4.y));
      pb.y = cvtpk_bf16(sigm(acc.b[2] + b4.z), sigm(acc.b[3] + b4.w));
      *(uint2*)(&gs[ml * XPAD + n0]) = pa;
      *(uint2*)(&gs[(16 + ml) * XPAD + n0]) = pb;
    }
  }
  __syncthreads();

  // ---- Phase B: gathered attention, one edge per wave-iteration ----
  const int h = lane >> 4;
  const int kvo = h * 64 + (lane & 15) * 2;
  const float scale = 0.17677669529663687f;  // 1/sqrt(32)

#pragma unroll 1
  for (int it = 0; it < 8; ++it) {
    const int le = wid * 8 + it;
    int e = (int)e0 + le;
    e = __builtin_amdgcn_readfirstlane(e);   // wave-uniform -> SGPR

    const uint32_t q2 = *(const uint32_t*)(&qs[le * XPAD + 2 * lane]);
    const uint32_t g2 = *(const uint32_t*)(&gs[le * XPAD + 2 * lane]);
    const float q0 = bflo(q2), q1 = bfhi(q2);

    float sc[MAXK];
    uint32_t vvm[MAXK];
    const int* kl = klist + (size_t)e * 32;
#pragma unroll
    for (int nb = 0; nb < MAXK; ++nb) {
      const int ii = kl[nb];
      const int jj = kl[16 + nb];
      const bool valid = (ii >= 0);
      const int is = valid ? ii : 0;
      const int js = valid ? jj : 0;
      const u16* kvrow = kvb + (size_t)is * 256;
      uint32_t kki = *(const uint32_t*)(kvrow + kvo);        // k pair
      uint32_t vvi = *(const uint32_t*)(kvrow + kvo + 32);   // v pair
      float p = q0 * bflo(kki) + q1 * bfhi(kki);
      p = row16_sum(p);                                      // head-wide dot
      float bj = bb[(size_t)js * 4 + h];
      sc[nb]  = valid ? (scale * p + bj) : 0.0f;
      vvm[nb] = valid ? vvi : 0u;
    }

    float m = sc[0];
#pragma unroll
    for (int nb = 1; nb < MAXK; ++nb) m = fmaxf(m, sc[nb]);
    float s = 0.f, a0 = 0.f, a1 = 0.f;
#pragma unroll
    for (int nb = 0; nb < MAXK; ++nb) {
      float al = __expf(sc[nb] - m);
      s += al;
      a0 += al * bflo(vvm[nb]);
      a1 += al * bfhi(vvm[nb]);
    }
    float inv = 1.0f / s;
    uint32_t xo = cvtpk_bf16(bflo(g2) * a0 * inv, bfhi(g2) * a1 * inv);
    *(uint32_t*)(&qs[le * XPAD + 2 * lane]) = xo;   // x overwrites q (aliased)
  }

  __syncthreads();

  // ---- Phase C: output GEMM, 32 edges x 128 out, K = 128 ----
  bf16x8 xfr[2][4];
#pragma unroll
  for (int s = 0; s < 2; ++s) {
#pragma unroll
    for (int kk = 0; kk < 4; ++kk)
      xfr[s][kk] = *(const bf16x8*)(&qs[(s * 16 + ml) * XPAD + kk * 32 + blk * 8]);
  }

  const long eA = e0 + ml, eB = e0 + 16 + ml;

#pragma unroll
  for (int t = 0; t < 2; ++t) {
    const int nt = wid * 2 + t;
    AccPair acc = tile_mm(Woutb, nt * 16, ml, blk, xfr, 128);
    const int o0 = nt * 16 + blk * 4;
    float4 b4 = *(const float4*)(bout + o0);
    float4 ra = make_float4(acc.a[0] + b4.x, acc.a[1] + b4.y,
                            acc.a[2] + b4.z, acc.a[3] + b4.w);
    float4 rb = make_float4(acc.b[0] + b4.x, acc.b[1] + b4.y,
                            acc.b[2] + b4.z, acc.b[3] + b4.w);
    *(float4*)(out + eA * 128 + o0) = ra;
    *(float4*)(out + eB * 128 + o0) = rb;
  }
}

// ---------------------------------------------------------------------------
extern "C" void kernel_launch(void* const* d_in, const int* in_sizes, int n_in,
                              void* d_out, int out_size, void* d_ws, size_t ws_size,
                              hipStream_t stream) {
  const float* Z     = (const float*)d_in[0];
  const int*   klist = (const int*)  d_in[1];
  const float* Wq    = (const float*)d_in[2];
  const float* Wk    = (const float*)d_in[3];
  const float* Wv    = (const float*)d_in[4];
  const float* Wb    = (const float*)d_in[5];
  const float* Wg    = (const float*)d_in[6];
  const float* bg    = (const float*)d_in[7];
  const float* Wout  = (const float*)d_in[8];
  const float* bout  = (const float*)d_in[9];
  float* out = (float*)d_out;

  char* ws = (char*)d_ws;
  u16*   Wc    = (u16*)(ws);                        //   528*128*2   = 135168
  u16*   Woutb = (u16*)(ws + 135168);               //   128*128*2   =  32768
  u16*   kvb   = (u16*)(ws + 167936);               // E*256*2 = 102.4 MB
  float* bb    = (float*)(ws + 102567936);          // E*4*4   = 3.2 MB

  prep_kernel<<<(NPAD * INF + OUTF * 128 + 255) / 256, 256, 0, stream>>>(
      Wq, Wk, Wv, Wb, Wg, Wout, Wc, Woutb);
  proj_kernel<<<EDGES / 64, 256, 0, stream>>>(
      Z, Wc, kvb, bb);
  attn_out_kernel<<<EDGES / 32, 256, 0, stream>>>(
      Z, Wc, bg, klist, kvb, bb, Woutb, bout, out);
}